// Round 7
// baseline (911.049 us; speedup 1.0000x reference)
//
#include <hip/hip_runtime.h>
#include <hip/hip_fp16.h>
#include <math.h>

#define F 512
#define H 16
#define C 7

typedef _Float16 h2 __attribute__((ext_vector_type(2)));

__device__ __forceinline__ h2 as_h2(unsigned u) { return __builtin_bit_cast(h2, u); }
__device__ __forceinline__ unsigned as_u32(h2 v) { return __builtin_bit_cast(unsigned, v); }

__device__ __forceinline__ float dot2acc(h2 a, h2 b, float c) {
#if __has_builtin(__builtin_amdgcn_fdot2)
    return __builtin_amdgcn_fdot2(a, b, c, false);
#else
    return c + (float)a[0] * (float)b[0] + (float)a[1] * (float)b[1];
#endif
}

// ---------------- utility ----------------
__global__ void zero_i32(int* p, int n) {
    int i = blockIdx.x * blockDim.x + threadIdx.x;
    if (i < n) p[i] = 0;
}

// ---------------- CSR build v2: direct atomics (count -> scan -> place) ----------------
__global__ __launch_bounds__(256) void count_edges(const int* __restrict__ ei, int E, int Etot,
                                                   int* __restrict__ rp) {
    int stride = gridDim.x * blockDim.x;
    for (int e = blockIdx.x * blockDim.x + threadIdx.x; e < Etot; e += stride) {
        int dst = (e < E) ? ei[E + e] : (e - E);
        atomicAdd(&rp[dst + 1], 1);
    }
}

// inclusive scan of rp[0..n) in chunks of 1024 (256T x 4); chunk total -> bsum[b]
__global__ __launch_bounds__(256) void scan_chunk(int* __restrict__ rp, int n,
                                                  int* __restrict__ bsum) {
    __shared__ int s[256];
    int b = blockIdx.x, t = threadIdx.x;
    int base = b * 1024 + t * 4;
    int v0 = 0, v1 = 0, v2 = 0, v3 = 0;
    if (base + 3 < n) {
        int4 q = *(const int4*)(rp + base);
        v0 = q.x; v1 = q.y; v2 = q.z; v3 = q.w;
    } else {
        if (base < n)     v0 = rp[base];
        if (base + 1 < n) v1 = rp[base + 1];
        if (base + 2 < n) v2 = rp[base + 2];
        if (base + 3 < n) v3 = rp[base + 3];
    }
    v1 += v0; v2 += v1; v3 += v2;
    s[t] = v3;
    __syncthreads();
    for (int d = 1; d < 256; d <<= 1) {
        int add = (t >= d) ? s[t - d] : 0;
        __syncthreads();
        s[t] += add;
        __syncthreads();
    }
    int excl = s[t] - v3;
    v0 += excl; v1 += excl; v2 += excl; v3 += excl;
    if (base + 3 < n) {
        int4 q; q.x = v0; q.y = v1; q.z = v2; q.w = v3;
        *(int4*)(rp + base) = q;
    } else {
        if (base < n)     rp[base] = v0;
        if (base + 1 < n) rp[base + 1] = v1;
        if (base + 2 < n) rp[base + 2] = v2;
        if (base + 3 < n) rp[base + 3] = v3;
    }
    if (t == 255) bsum[b] = s[255];
}

__global__ void scan_top(int* __restrict__ bsum, int nb) {
    __shared__ int s[128];
    int t = threadIdx.x;
    int v = (t < nb) ? bsum[t] : 0;
    s[t] = v;
    __syncthreads();
    for (int d = 1; d < 128; d <<= 1) {
        int a = (t >= d) ? s[t - d] : 0;
        __syncthreads();
        s[t] += a;
        __syncthreads();
    }
    if (t < nb) bsum[t] = s[t] - v;   // exclusive prefix of chunk totals
}

// add chunk base; also seed cur[] = final rp[] (place uses absolute cursors)
__global__ __launch_bounds__(256) void scan_add(int* __restrict__ rp, int n,
                                                const int* __restrict__ bsum,
                                                int* __restrict__ cur, int N) {
    int b = blockIdx.x, t = threadIdx.x;
    int add = bsum[b];
    int base = b * 1024 + t * 4;
#pragma unroll
    for (int k = 0; k < 4; ++k) {
        int idx = base + k;
        if (idx < n) {
            int v = rp[idx] + add;
            if (add) rp[idx] = v;
            if (idx < N) cur[idx] = v;
        }
    }
}

__global__ __launch_bounds__(256) void place_edges(const int* __restrict__ ei, int E, int Etot,
                                                   int* __restrict__ cur, int* __restrict__ srcs) {
    int stride = gridDim.x * blockDim.x;
    for (int e = blockIdx.x * blockDim.x + threadIdx.x; e < Etot; e += stride) {
        int src, dst;
        if (e < E) { src = ei[e]; dst = ei[E + e]; }
        else       { src = e - E; dst = src; }
        int pos = atomicAdd(&cur[dst], 1);
        srcs[pos] = src;
    }
}

// ---------------- lin1: h = relu(x@W1^T+b1); write combined row [hn fp16 x16 | h fp16 x16] ----------------
__global__ __launch_bounds__(256) void lin1_relu(const float* __restrict__ x,
                                                 const float* __restrict__ W1,
                                                 const float* __restrict__ b1,
                                                 __half* __restrict__ hrow, int N) {
    __shared__ float4 w4[16 * 16 * 9];  // [j][s][m], slice stride 9 float4
    int t = threadIdx.x;
    for (int r = 0; r < 8; ++r) {
        int idx = r * 256 + t;
        int j = idx >> 7;
        int rem = idx & 127;
        int s = rem >> 3, m = rem & 7;
        w4[(j * 16 + s) * 9 + m] = ((const float4*)W1)[idx];
    }
    __syncthreads();

    int s = t & 15, g = t >> 4;
    int iA = blockIdx.x * 32 + g;
    int iB = iA + 16;
    int iAc = min(iA, N - 1), iBc = min(iB, N - 1);

    const float4* xA4 = (const float4*)(x + (size_t)iAc * F);
    const float4* xB4 = (const float4*)(x + (size_t)iBc * F);
    float4 xa[8], xb[8];
#pragma unroll
    for (int m = 0; m < 8; ++m) xa[m] = xA4[s * 8 + m];
#pragma unroll
    for (int m = 0; m < 8; ++m) xb[m] = xB4[s * 8 + m];

    float vA[16], vB[16];
#pragma unroll
    for (int j = 0; j < 16; ++j) { vA[j] = 0.f; vB[j] = 0.f; }
#pragma unroll
    for (int j = 0; j < 16; ++j) {
        const float4* wr = &w4[(j * 16 + s) * 9];
#pragma unroll
        for (int m = 0; m < 8; ++m) {
            float4 w = wr[m];
            vA[j] += w.x * xa[m].x + w.y * xa[m].y + w.z * xa[m].z + w.w * xa[m].w;
            vB[j] += w.x * xb[m].x + w.y * xb[m].y + w.z * xb[m].z + w.w * xb[m].w;
        }
    }

#pragma unroll
    for (int st = 0; st < 4; ++st) {
        int bit = (s >> st) & 1;
        int cntj = 16 >> (st + 1);
#pragma unroll
        for (int k = 0; k < 8; ++k) {
            if (k < cntj) {
                float keepA = bit ? vA[2 * k + 1] : vA[2 * k];
                float giveA = bit ? vA[2 * k] : vA[2 * k + 1];
                vA[k] = keepA + __shfl_xor(giveA, 1 << st);
                float keepB = bit ? vB[2 * k + 1] : vB[2 * k];
                float giveB = bit ? vB[2 * k] : vB[2 * k + 1];
                vB[k] = keepB + __shfl_xor(giveB, 1 << st);
            }
        }
    }

    float bs = b1[s];
    float oA = fmaxf(vA[0] + bs, 0.f);
    float oB = fmaxf(vB[0] + bs, 0.f);

    float sqA = oA * oA, sqB = oB * oB;
    sqA += __shfl_xor(sqA, 1); sqA += __shfl_xor(sqA, 2);
    sqA += __shfl_xor(sqA, 4); sqA += __shfl_xor(sqA, 8);
    sqB += __shfl_xor(sqB, 1); sqB += __shfl_xor(sqB, 2);
    sqB += __shfl_xor(sqB, 4); sqB += __shfl_xor(sqB, 8);
    float rnA = 1.0f / fmaxf(sqrtf(sqA), 1e-12f);
    float rnB = 1.0f / fmaxf(sqrtf(sqB), 1e-12f);

    if (iA < N) {
        hrow[(size_t)iA * 32 + s] = __float2half(oA * rnA);
        hrow[(size_t)iA * 32 + 16 + s] = __float2half(oA);
    }
    if (iB < N) {
        hrow[(size_t)iB * 32 + s] = __float2half(oB * rnB);
        hrow[(size_t)iB * 32 + 16 + s] = __float2half(oB);
    }
}

// ---------------- AGNN step v5 (r4 champion, untouched): 4 sub-lanes per dst, 64B rows ----------------
__global__ __launch_bounds__(256) void agnn_step(const uint4* __restrict__ hrow,
                                                 const int* __restrict__ rp,
                                                 const int* __restrict__ srcs,
                                                 const float* __restrict__ bp,
                                                 uint4* __restrict__ hrow_out, int N) {
    int t = threadIdx.x;
    int sub = t & 3, g = t >> 2;
    int i = blockIdx.x * 64 + g;
    if (i >= N) return;

    const float L2E = 1.4426950408889634f;
    float beta = bp ? bp[0] : 1.0f;
    float aL = beta * L2E;
    float mm = fabsf(beta) * L2E;

    // own normalized row (first 32B)
    uint4 hA = hrow[(size_t)i * 4 + 0];
    uint4 hB = hrow[(size_t)i * 4 + 1];
    h2 hi[8];
    hi[0] = as_h2(hA.x); hi[1] = as_h2(hA.y); hi[2] = as_h2(hA.z); hi[3] = as_h2(hA.w);
    hi[4] = as_h2(hB.x); hi[5] = as_h2(hB.y); hi[6] = as_h2(hB.z); hi[7] = as_h2(hB.w);

    int e0 = rp[i];
    int deg = rp[i + 1] - e0;
    int dm1 = deg - 1;
    int U = (deg + 3) >> 2;   // uniform across the 4 sub-lanes of this dst

    // ring: slot u holds row of edge m=mb+u (lane edge k = sub+4m); sbuf[u] = src of edge m+4
    int sbuf[4];
    uint4 rbuf[4][4];
#pragma unroll
    for (int u = 0; u < 4; ++u) {
        int s = srcs[e0 + min(sub + 4 * u, dm1)];
        const uint4* r = hrow + (size_t)s * 4;
        rbuf[u][0] = r[0]; rbuf[u][1] = r[1]; rbuf[u][2] = r[2]; rbuf[u][3] = r[3];
        sbuf[u] = srcs[e0 + min(sub + 4 * (u + 4), dm1)];
    }

    float denom = 0.f;
    float acc[16];
#pragma unroll
    for (int j = 0; j < 16; ++j) acc[j] = 0.f;

    for (int mb = 0; mb < U; mb += 4) {
#pragma unroll
        for (int u = 0; u < 4; ++u) {
            int m = mb + u;
            int k = sub + 4 * m;
            uint4 a = rbuf[u][0], b = rbuf[u][1], c = rbuf[u][2], d = rbuf[u][3];
            // refill slot u with row of edge m+4; prefetch src of edge m+8
            int snext = sbuf[u];
            sbuf[u] = srcs[e0 + min(sub + 4 * (m + 8), dm1)];
            const uint4* r = hrow + (size_t)snext * 4;
            rbuf[u][0] = r[0]; rbuf[u][1] = r[1]; rbuf[u][2] = r[2]; rbuf[u][3] = r[3];

            float dot = 0.f;
            dot = dot2acc(hi[0], as_h2(a.x), dot);
            dot = dot2acc(hi[1], as_h2(a.y), dot);
            dot = dot2acc(hi[2], as_h2(a.z), dot);
            dot = dot2acc(hi[3], as_h2(a.w), dot);
            dot = dot2acc(hi[4], as_h2(b.x), dot);
            dot = dot2acc(hi[5], as_h2(b.y), dot);
            dot = dot2acc(hi[6], as_h2(b.z), dot);
            dot = dot2acc(hi[7], as_h2(b.w), dot);

            float w = exp2f(fmaf(aL, dot, -mm));
            w = (k < deg) ? w : 0.f;
            denom += w;

            h2 c0 = as_h2(c.x), c1 = as_h2(c.y), c2 = as_h2(c.z), c3 = as_h2(c.w);
            h2 d0 = as_h2(d.x), d1 = as_h2(d.y), d2 = as_h2(d.z), d3 = as_h2(d.w);
            acc[0]  = fmaf(w, (float)c0[0], acc[0]);
            acc[1]  = fmaf(w, (float)c0[1], acc[1]);
            acc[2]  = fmaf(w, (float)c1[0], acc[2]);
            acc[3]  = fmaf(w, (float)c1[1], acc[3]);
            acc[4]  = fmaf(w, (float)c2[0], acc[4]);
            acc[5]  = fmaf(w, (float)c2[1], acc[5]);
            acc[6]  = fmaf(w, (float)c3[0], acc[6]);
            acc[7]  = fmaf(w, (float)c3[1], acc[7]);
            acc[8]  = fmaf(w, (float)d0[0], acc[8]);
            acc[9]  = fmaf(w, (float)d0[1], acc[9]);
            acc[10] = fmaf(w, (float)d1[0], acc[10]);
            acc[11] = fmaf(w, (float)d1[1], acc[11]);
            acc[12] = fmaf(w, (float)d2[0], acc[12]);
            acc[13] = fmaf(w, (float)d2[1], acc[13]);
            acc[14] = fmaf(w, (float)d3[0], acc[14]);
            acc[15] = fmaf(w, (float)d3[1], acc[15]);
        }
    }

    // combine the 4 sub-lanes (lanes 4g..4g+3)
    denom += __shfl_xor(denom, 1);
    denom += __shfl_xor(denom, 2);
#pragma unroll
    for (int j = 0; j < 16; ++j) {
        acc[j] += __shfl_xor(acc[j], 1);
        acc[j] += __shfl_xor(acc[j], 2);
    }

    float rd = 1.0f / denom;
    float o[16];
    float sq = 0.f;
#pragma unroll
    for (int j = 0; j < 16; ++j) {
        o[j] = acc[j] * rd;
        sq = fmaf(o[j], o[j], sq);
    }
    float rno = 1.0f / fmaxf(sqrtf(sq), 1e-12f);

    // each sub-lane writes one 16B quarter: sub0=hn[0..7], sub1=hn[8..15], sub2=h[0..7], sub3=h[8..15]
    float scale = (sub < 2) ? rno : 1.0f;
    int half = (sub & 1) * 8;
    uint4 wq;
    {
        h2 t0, t1;
        t0[0] = (_Float16)(o[half + 0] * scale); t0[1] = (_Float16)(o[half + 1] * scale);
        t1[0] = (_Float16)(o[half + 2] * scale); t1[1] = (_Float16)(o[half + 3] * scale);
        wq.x = as_u32(t0); wq.y = as_u32(t1);
        t0[0] = (_Float16)(o[half + 4] * scale); t0[1] = (_Float16)(o[half + 5] * scale);
        t1[0] = (_Float16)(o[half + 6] * scale); t1[1] = (_Float16)(o[half + 7] * scale);
        wq.z = as_u32(t0); wq.w = as_u32(t1);
    }
    hrow_out[(size_t)i * 4 + sub] = wq;
}

// ---------------- head: logits + log_softmax (reads h part of combined row) ----------------
__global__ __launch_bounds__(256) void head_kernel(const uint4* __restrict__ hrow,
                                                   const float* __restrict__ W2,
                                                   const float* __restrict__ b2,
                                                   float* __restrict__ out, int N) {
    __shared__ float w2[C * H];
    __shared__ float bb[C];
    int t = threadIdx.x;
    if (t < C * H) w2[t] = W2[t];
    if (t < C) bb[t] = b2[t];
    __syncthreads();
    int i = blockIdx.x * blockDim.x + t;
    if (i >= N) return;
    uint4 cA = hrow[(size_t)i * 4 + 2];
    uint4 cB = hrow[(size_t)i * 4 + 3];
    float hv[H];
    {
        h2 v;
        v = as_h2(cA.x); hv[0] = (float)v[0];  hv[1] = (float)v[1];
        v = as_h2(cA.y); hv[2] = (float)v[0];  hv[3] = (float)v[1];
        v = as_h2(cA.z); hv[4] = (float)v[0];  hv[5] = (float)v[1];
        v = as_h2(cA.w); hv[6] = (float)v[0];  hv[7] = (float)v[1];
        v = as_h2(cB.x); hv[8] = (float)v[0];  hv[9] = (float)v[1];
        v = as_h2(cB.y); hv[10] = (float)v[0]; hv[11] = (float)v[1];
        v = as_h2(cB.z); hv[12] = (float)v[0]; hv[13] = (float)v[1];
        v = as_h2(cB.w); hv[14] = (float)v[0]; hv[15] = (float)v[1];
    }
    float lg[C];
    float m = -1e30f;
#pragma unroll
    for (int c = 0; c < C; ++c) {
        float s = bb[c];
#pragma unroll
        for (int k = 0; k < H; ++k) s += hv[k] * w2[c * H + k];
        lg[c] = s;
        m = fmaxf(m, s);
    }
    float sum = 0.f;
#pragma unroll
    for (int c = 0; c < C; ++c) sum += expf(lg[c] - m);
    float lse = m + logf(sum);
    float* op = out + (size_t)i * C;
#pragma unroll
    for (int c = 0; c < C; ++c) op[c] = lg[c] - lse;
}

// ---------------- launch ----------------
extern "C" void kernel_launch(void* const* d_in, const int* in_sizes, int n_in,
                              void* d_out, int out_size, void* d_ws, size_t ws_size,
                              hipStream_t stream) {
    const float* x     = (const float*)d_in[0];
    const int*   ei    = (const int*)d_in[1];
    const float* W1    = (const float*)d_in[2];
    const float* b1    = (const float*)d_in[3];
    const float* beta2 = (const float*)d_in[4];
    const float* beta3 = (const float*)d_in[5];
    const float* beta4 = (const float*)d_in[6];
    const float* W2    = (const float*)d_in[7];
    const float* b2    = (const float*)d_in[8];
    float* out = (float*)d_out;

    int N = in_sizes[0] / F;     // 100000
    int E = in_sizes[1] / 2;     // 3200000
    int Etot = E + N;

    char* p = (char*)d_ws;
    uint4* hr_a = (uint4*)p; p += (size_t)N * 64;
    uint4* hr_b = (uint4*)p; p += (size_t)N * 64;
    int* rp     = (int*)p;   p += (size_t)(N + 1) * 4;
    int* cur    = (int*)p;   p += (size_t)N * 4;
    int* srcs   = (int*)p;   p += (size_t)Etot * 4;
    int* bsum   = (int*)p;   p += (size_t)128 * 4;

    int nb = (N + 1 + 1023) / 1024;   // scan chunks (98 for N=100000)

    // CSR build: count -> scan -> place (direct atomics, no binned intermediate)
    zero_i32<<<(N + 1 + 255) / 256, 256, 0, stream>>>(rp, N + 1);
    count_edges<<<2048, 256, 0, stream>>>(ei, E, Etot, rp);
    scan_chunk<<<nb, 256, 0, stream>>>(rp, N + 1, bsum);
    scan_top<<<1, 128, 0, stream>>>(bsum, nb);
    scan_add<<<nb, 256, 0, stream>>>(rp, N + 1, bsum, cur, N);
    place_edges<<<2048, 256, 0, stream>>>(ei, E, Etot, cur, srcs);

    // lin1 -> combined rows
    lin1_relu<<<(N + 31) / 32, 256, 0, stream>>>(x, W1, b1, (__half*)hr_a, N);

    // 4 AGNN steps (4 sub-lanes per dst)
    int gs = (N + 63) / 64;
    agnn_step<<<gs, 256, 0, stream>>>(hr_a, rp, srcs, nullptr, hr_b, N);
    agnn_step<<<gs, 256, 0, stream>>>(hr_b, rp, srcs, beta2, hr_a, N);
    agnn_step<<<gs, 256, 0, stream>>>(hr_a, rp, srcs, beta3, hr_b, N);
    agnn_step<<<gs, 256, 0, stream>>>(hr_b, rp, srcs, beta4, hr_a, N);

    // head
    head_kernel<<<(N + 255) / 256, 256, 0, stream>>>(hr_a, W2, b2, out, N);
}

// Round 8
// 744.868 us; speedup vs baseline: 1.2231x; 1.2231x over previous
//
#include <hip/hip_runtime.h>
#include <hip/hip_fp16.h>
#include <math.h>

#define F 512
#define H 16
#define C 7
#define NB 512          // coarse buckets for CSR build
#define BIN_CHUNK 4096  // edges per block in bin_edges
#define BIN_T 512       // threads per bin_edges block (8 waves -> occupancy fix, r4 win)

typedef _Float16 h2 __attribute__((ext_vector_type(2)));

__device__ __forceinline__ h2 as_h2(unsigned u) { return __builtin_bit_cast(h2, u); }
__device__ __forceinline__ unsigned as_u32(h2 v) { return __builtin_bit_cast(unsigned, v); }

__device__ __forceinline__ float dot2acc(h2 a, h2 b, float c) {
#if __has_builtin(__builtin_amdgcn_fdot2)
    return __builtin_amdgcn_fdot2(a, b, c, false);
#else
    return c + (float)a[0] * (float)b[0] + (float)a[1] * (float)b[1];
#endif
}

// ---------------- utility ----------------
__global__ void zero_i32(int* p, int n) {
    int i = blockIdx.x * blockDim.x + threadIdx.x;
    if (i < n) p[i] = 0;
}

// ---------------- CSR build: 3 kernels, fixed-capacity buckets (r4 champion) ----------------
__global__ __launch_bounds__(BIN_T) void bin_edges(const int* __restrict__ ei, int E, int Etot,
                                                   int width, int cap, int* __restrict__ gcnt,
                                                   unsigned* __restrict__ binned) {
    __shared__ int cnt[NB];
    __shared__ int base[NB];
    int t = threadIdx.x;
    for (int i = t; i < NB; i += BIN_T) cnt[i] = 0;
    __syncthreads();
    long chunk0 = (long)blockIdx.x * BIN_CHUNK;
    for (int k = 0; k < BIN_CHUNK / BIN_T; ++k) {
        long e = chunk0 + k * BIN_T + t;
        if (e < Etot) {
            int dst = (e < E) ? ei[E + e] : (int)(e - E);
            atomicAdd(&cnt[dst / width], 1);
        }
    }
    __syncthreads();
    for (int i = t; i < NB; i += BIN_T) {
        int c = cnt[i];
        base[i] = c ? atomicAdd(&gcnt[i], c) : 0;
        cnt[i] = 0;
    }
    __syncthreads();
    for (int k = 0; k < BIN_CHUNK / BIN_T; ++k) {
        long e = chunk0 + k * BIN_T + t;
        if (e < Etot) {
            int src, dst;
            if (e < E) { src = ei[e]; dst = ei[E + e]; }
            else       { src = (int)(e - E); dst = src; }
            int b = dst / width;
            size_t pos = (size_t)b * cap + base[b] + atomicAdd(&cnt[b], 1);
            binned[pos] = (unsigned)src | ((unsigned)(dst - b * width) << 17);
        }
    }
}

__global__ void bucket_scan(const int* __restrict__ gcnt, int Etot,
                            int* __restrict__ bbase, int* __restrict__ rp, int N) {
    __shared__ int s[NB];
    int t = threadIdx.x;
    int own = gcnt[t];
    s[t] = own;
    __syncthreads();
    for (int d = 1; d < NB; d <<= 1) {
        int add = (t >= d) ? s[t - d] : 0;
        __syncthreads();
        s[t] += add;
        __syncthreads();
    }
    bbase[t] = s[t] - own;
    if (t == NB - 1) bbase[NB] = s[t];
    if (t == 0) rp[N] = Etot;
}

__global__ __launch_bounds__(256) void bucket_sort(const unsigned* __restrict__ binned,
                                                   const int* __restrict__ gcnt,
                                                   const int* __restrict__ bbase,
                                                   int width, int cap, int N,
                                                   int* __restrict__ rp, int* __restrict__ srcs) {
    __shared__ int cnt[256];
    __shared__ int cur[256];
    int b = blockIdx.x, t = threadIdx.x;
    int r0 = bbase[b];
    int ne = gcnt[b];
    const unsigned* bin = binned + (size_t)b * cap;
    int nodeBase = b * width;
    cnt[t] = 0;
    cur[t] = 0;
    __syncthreads();
    for (int e = t; e < ne; e += 256) {
        atomicAdd(&cnt[bin[e] >> 17], 1);
    }
    __syncthreads();
    int own = cnt[t];
    for (int d = 1; d < 256; d <<= 1) {
        int add = (t >= d) ? cnt[t - d] : 0;
        __syncthreads();
        cnt[t] += add;
        __syncthreads();
    }
    int excl = cnt[t] - own;
    int node = nodeBase + t;
    if (t < width && node < N) rp[node] = r0 + excl;
    __syncthreads();
    cnt[t] = excl;
    __syncthreads();
    for (int e = t; e < ne; e += 256) {
        unsigned p = bin[e];
        int dL = p >> 17;
        int pos = r0 + cnt[dL] + atomicAdd(&cur[dL], 1);
        srcs[pos] = (int)(p & 0x1FFFFu);
    }
}

// ---------------- lin1: h = relu(x@W1^T+b1); write combined row [hn fp16 x16 | h fp16 x16] ----------------
__global__ __launch_bounds__(256) void lin1_relu(const float* __restrict__ x,
                                                 const float* __restrict__ W1,
                                                 const float* __restrict__ b1,
                                                 __half* __restrict__ hrow, int N) {
    __shared__ float4 w4[16 * 16 * 9];  // [j][s][m], slice stride 9 float4
    int t = threadIdx.x;
    for (int r = 0; r < 8; ++r) {
        int idx = r * 256 + t;
        int j = idx >> 7;
        int rem = idx & 127;
        int s = rem >> 3, m = rem & 7;
        w4[(j * 16 + s) * 9 + m] = ((const float4*)W1)[idx];
    }
    __syncthreads();

    int s = t & 15, g = t >> 4;
    int iA = blockIdx.x * 32 + g;
    int iB = iA + 16;
    int iAc = min(iA, N - 1), iBc = min(iB, N - 1);

    const float4* xA4 = (const float4*)(x + (size_t)iAc * F);
    const float4* xB4 = (const float4*)(x + (size_t)iBc * F);
    float4 xa[8], xb[8];
#pragma unroll
    for (int m = 0; m < 8; ++m) xa[m] = xA4[s * 8 + m];
#pragma unroll
    for (int m = 0; m < 8; ++m) xb[m] = xB4[s * 8 + m];

    float vA[16], vB[16];
#pragma unroll
    for (int j = 0; j < 16; ++j) { vA[j] = 0.f; vB[j] = 0.f; }
#pragma unroll
    for (int j = 0; j < 16; ++j) {
        const float4* wr = &w4[(j * 16 + s) * 9];
#pragma unroll
        for (int m = 0; m < 8; ++m) {
            float4 w = wr[m];
            vA[j] += w.x * xa[m].x + w.y * xa[m].y + w.z * xa[m].z + w.w * xa[m].w;
            vB[j] += w.x * xb[m].x + w.y * xb[m].y + w.z * xb[m].z + w.w * xb[m].w;
        }
    }

#pragma unroll
    for (int st = 0; st < 4; ++st) {
        int bit = (s >> st) & 1;
        int cntj = 16 >> (st + 1);
#pragma unroll
        for (int k = 0; k < 8; ++k) {
            if (k < cntj) {
                float keepA = bit ? vA[2 * k + 1] : vA[2 * k];
                float giveA = bit ? vA[2 * k] : vA[2 * k + 1];
                vA[k] = keepA + __shfl_xor(giveA, 1 << st);
                float keepB = bit ? vB[2 * k + 1] : vB[2 * k];
                float giveB = bit ? vB[2 * k] : vB[2 * k + 1];
                vB[k] = keepB + __shfl_xor(giveB, 1 << st);
            }
        }
    }

    float bs = b1[s];
    float oA = fmaxf(vA[0] + bs, 0.f);
    float oB = fmaxf(vB[0] + bs, 0.f);

    float sqA = oA * oA, sqB = oB * oB;
    sqA += __shfl_xor(sqA, 1); sqA += __shfl_xor(sqA, 2);
    sqA += __shfl_xor(sqA, 4); sqA += __shfl_xor(sqA, 8);
    sqB += __shfl_xor(sqB, 1); sqB += __shfl_xor(sqB, 2);
    sqB += __shfl_xor(sqB, 4); sqB += __shfl_xor(sqB, 8);
    float rnA = 1.0f / fmaxf(sqrtf(sqA), 1e-12f);
    float rnB = 1.0f / fmaxf(sqrtf(sqB), 1e-12f);

    if (iA < N) {
        hrow[(size_t)iA * 32 + s] = __float2half(oA * rnA);
        hrow[(size_t)iA * 32 + 16 + s] = __float2half(oA);
    }
    if (iB < N) {
        hrow[(size_t)iB * 32 + s] = __float2half(oB * rnB);
        hrow[(size_t)iB * 32 + 16 + s] = __float2half(oB);
    }
}

// ---------------- AGNN step v5 + forced 4 waves/EU: 4 sub-lanes per dst, 64B rows ----------------
// Inner loop byte-identical to the r4 591us champion; __launch_bounds__(256,4) caps VGPR at 128
// (ring 64 + hi 8 + acc 16 + sbuf 4 + temps fits) -> 4 blocks/CU instead of 3 (+33% TLP).
__global__ __launch_bounds__(256, 4) void agnn_step(const uint4* __restrict__ hrow,
                                                    const int* __restrict__ rp,
                                                    const int* __restrict__ srcs,
                                                    const float* __restrict__ bp,
                                                    uint4* __restrict__ hrow_out, int N) {
    int t = threadIdx.x;
    int sub = t & 3, g = t >> 2;
    int i = blockIdx.x * 64 + g;
    if (i >= N) return;

    const float L2E = 1.4426950408889634f;
    float beta = bp ? bp[0] : 1.0f;
    float aL = beta * L2E;
    float mm = fabsf(beta) * L2E;

    // own normalized row (first 32B)
    uint4 hA = hrow[(size_t)i * 4 + 0];
    uint4 hB = hrow[(size_t)i * 4 + 1];
    h2 hi[8];
    hi[0] = as_h2(hA.x); hi[1] = as_h2(hA.y); hi[2] = as_h2(hA.z); hi[3] = as_h2(hA.w);
    hi[4] = as_h2(hB.x); hi[5] = as_h2(hB.y); hi[6] = as_h2(hB.z); hi[7] = as_h2(hB.w);

    int e0 = rp[i];
    int deg = rp[i + 1] - e0;
    int dm1 = deg - 1;
    int U = (deg + 3) >> 2;   // uniform across the 4 sub-lanes of this dst

    // ring: slot u holds row of edge m=mb+u (lane edge k = sub+4m); sbuf[u] = src of edge m+4
    int sbuf[4];
    uint4 rbuf[4][4];
#pragma unroll
    for (int u = 0; u < 4; ++u) {
        int s = srcs[e0 + min(sub + 4 * u, dm1)];
        const uint4* r = hrow + (size_t)s * 4;
        rbuf[u][0] = r[0]; rbuf[u][1] = r[1]; rbuf[u][2] = r[2]; rbuf[u][3] = r[3];
        sbuf[u] = srcs[e0 + min(sub + 4 * (u + 4), dm1)];
    }

    float denom = 0.f;
    float acc[16];
#pragma unroll
    for (int j = 0; j < 16; ++j) acc[j] = 0.f;

    for (int mb = 0; mb < U; mb += 4) {
#pragma unroll
        for (int u = 0; u < 4; ++u) {
            int m = mb + u;
            int k = sub + 4 * m;
            uint4 a = rbuf[u][0], b = rbuf[u][1], c = rbuf[u][2], d = rbuf[u][3];
            // refill slot u with row of edge m+4; prefetch src of edge m+8
            int snext = sbuf[u];
            sbuf[u] = srcs[e0 + min(sub + 4 * (m + 8), dm1)];
            const uint4* r = hrow + (size_t)snext * 4;
            rbuf[u][0] = r[0]; rbuf[u][1] = r[1]; rbuf[u][2] = r[2]; rbuf[u][3] = r[3];

            float dot = 0.f;
            dot = dot2acc(hi[0], as_h2(a.x), dot);
            dot = dot2acc(hi[1], as_h2(a.y), dot);
            dot = dot2acc(hi[2], as_h2(a.z), dot);
            dot = dot2acc(hi[3], as_h2(a.w), dot);
            dot = dot2acc(hi[4], as_h2(b.x), dot);
            dot = dot2acc(hi[5], as_h2(b.y), dot);
            dot = dot2acc(hi[6], as_h2(b.z), dot);
            dot = dot2acc(hi[7], as_h2(b.w), dot);

            float w = exp2f(fmaf(aL, dot, -mm));
            w = (k < deg) ? w : 0.f;
            denom += w;

            h2 c0 = as_h2(c.x), c1 = as_h2(c.y), c2 = as_h2(c.z), c3 = as_h2(c.w);
            h2 d0 = as_h2(d.x), d1 = as_h2(d.y), d2 = as_h2(d.z), d3 = as_h2(d.w);
            acc[0]  = fmaf(w, (float)c0[0], acc[0]);
            acc[1]  = fmaf(w, (float)c0[1], acc[1]);
            acc[2]  = fmaf(w, (float)c1[0], acc[2]);
            acc[3]  = fmaf(w, (float)c1[1], acc[3]);
            acc[4]  = fmaf(w, (float)c2[0], acc[4]);
            acc[5]  = fmaf(w, (float)c2[1], acc[5]);
            acc[6]  = fmaf(w, (float)c3[0], acc[6]);
            acc[7]  = fmaf(w, (float)c3[1], acc[7]);
            acc[8]  = fmaf(w, (float)d0[0], acc[8]);
            acc[9]  = fmaf(w, (float)d0[1], acc[9]);
            acc[10] = fmaf(w, (float)d1[0], acc[10]);
            acc[11] = fmaf(w, (float)d1[1], acc[11]);
            acc[12] = fmaf(w, (float)d2[0], acc[12]);
            acc[13] = fmaf(w, (float)d2[1], acc[13]);
            acc[14] = fmaf(w, (float)d3[0], acc[14]);
            acc[15] = fmaf(w, (float)d3[1], acc[15]);
        }
    }

    // combine the 4 sub-lanes (lanes 4g..4g+3)
    denom += __shfl_xor(denom, 1);
    denom += __shfl_xor(denom, 2);
#pragma unroll
    for (int j = 0; j < 16; ++j) {
        acc[j] += __shfl_xor(acc[j], 1);
        acc[j] += __shfl_xor(acc[j], 2);
    }

    float rd = 1.0f / denom;
    float o[16];
    float sq = 0.f;
#pragma unroll
    for (int j = 0; j < 16; ++j) {
        o[j] = acc[j] * rd;
        sq = fmaf(o[j], o[j], sq);
    }
    float rno = 1.0f / fmaxf(sqrtf(sq), 1e-12f);

    // each sub-lane writes one 16B quarter: sub0=hn[0..7], sub1=hn[8..15], sub2=h[0..7], sub3=h[8..15]
    float scale = (sub < 2) ? rno : 1.0f;
    int half = (sub & 1) * 8;
    uint4 wq;
    {
        h2 t0, t1;
        t0[0] = (_Float16)(o[half + 0] * scale); t0[1] = (_Float16)(o[half + 1] * scale);
        t1[0] = (_Float16)(o[half + 2] * scale); t1[1] = (_Float16)(o[half + 3] * scale);
        wq.x = as_u32(t0); wq.y = as_u32(t1);
        t0[0] = (_Float16)(o[half + 4] * scale); t0[1] = (_Float16)(o[half + 5] * scale);
        t1[0] = (_Float16)(o[half + 6] * scale); t1[1] = (_Float16)(o[half + 7] * scale);
        wq.z = as_u32(t0); wq.w = as_u32(t1);
    }
    hrow_out[(size_t)i * 4 + sub] = wq;
}

// ---------------- head: logits + log_softmax (reads h part of combined row) ----------------
__global__ __launch_bounds__(256) void head_kernel(const uint4* __restrict__ hrow,
                                                   const float* __restrict__ W2,
                                                   const float* __restrict__ b2,
                                                   float* __restrict__ out, int N) {
    __shared__ float w2[C * H];
    __shared__ float bb[C];
    int t = threadIdx.x;
    if (t < C * H) w2[t] = W2[t];
    if (t < C) bb[t] = b2[t];
    __syncthreads();
    int i = blockIdx.x * blockDim.x + t;
    if (i >= N) return;
    uint4 cA = hrow[(size_t)i * 4 + 2];
    uint4 cB = hrow[(size_t)i * 4 + 3];
    float hv[H];
    {
        h2 v;
        v = as_h2(cA.x); hv[0] = (float)v[0];  hv[1] = (float)v[1];
        v = as_h2(cA.y); hv[2] = (float)v[0];  hv[3] = (float)v[1];
        v = as_h2(cA.z); hv[4] = (float)v[0];  hv[5] = (float)v[1];
        v = as_h2(cA.w); hv[6] = (float)v[0];  hv[7] = (float)v[1];
        v = as_h2(cB.x); hv[8] = (float)v[0];  hv[9] = (float)v[1];
        v = as_h2(cB.y); hv[10] = (float)v[0]; hv[11] = (float)v[1];
        v = as_h2(cB.z); hv[12] = (float)v[0]; hv[13] = (float)v[1];
        v = as_h2(cB.w); hv[14] = (float)v[0]; hv[15] = (float)v[1];
    }
    float lg[C];
    float m = -1e30f;
#pragma unroll
    for (int c = 0; c < C; ++c) {
        float s = bb[c];
#pragma unroll
        for (int k = 0; k < H; ++k) s += hv[k] * w2[c * H + k];
        lg[c] = s;
        m = fmaxf(m, s);
    }
    float sum = 0.f;
#pragma unroll
    for (int c = 0; c < C; ++c) sum += expf(lg[c] - m);
    float lse = m + logf(sum);
    float* op = out + (size_t)i * C;
#pragma unroll
    for (int c = 0; c < C; ++c) op[c] = lg[c] - lse;
}

// ---------------- launch ----------------
extern "C" void kernel_launch(void* const* d_in, const int* in_sizes, int n_in,
                              void* d_out, int out_size, void* d_ws, size_t ws_size,
                              hipStream_t stream) {
    const float* x     = (const float*)d_in[0];
    const int*   ei    = (const int*)d_in[1];
    const float* W1    = (const float*)d_in[2];
    const float* b1    = (const float*)d_in[3];
    const float* beta2 = (const float*)d_in[4];
    const float* beta3 = (const float*)d_in[5];
    const float* beta4 = (const float*)d_in[6];
    const float* W2    = (const float*)d_in[7];
    const float* b2    = (const float*)d_in[8];
    float* out = (float*)d_out;

    int N = in_sizes[0] / F;     // 100000
    int E = in_sizes[1] / 2;     // 3200000
    int Etot = E + N;
    int width = (N + NB - 1) / NB;   // 196
    int cap = (Etot / NB) * 5 / 4;   // 1.25x mean bucket size (>20 sigma margin)

    char* p = (char*)d_ws;
    uint4* hr_a = (uint4*)p; p += (size_t)N * 64;
    uint4* hr_b = (uint4*)p; p += (size_t)N * 64;
    int* rp     = (int*)p;   p += (size_t)(N + 1) * 4;
    int* srcs   = (int*)p;   p += (size_t)Etot * 4;
    int* gcnt   = (int*)p;   p += (size_t)NB * 4;
    int* bbase  = (int*)p;   p += (size_t)(NB + 1) * 4;
    p = (char*)(((size_t)p + 255) & ~(size_t)255);
    unsigned* binned = (unsigned*)p; p += (size_t)NB * cap * 4;

    // CSR build
    zero_i32<<<(NB + 255) / 256, 256, 0, stream>>>(gcnt, NB);
    bin_edges<<<(Etot + BIN_CHUNK - 1) / BIN_CHUNK, BIN_T, 0, stream>>>(ei, E, Etot, width, cap, gcnt, binned);
    bucket_scan<<<1, NB, 0, stream>>>(gcnt, Etot, bbase, rp, N);
    bucket_sort<<<NB, 256, 0, stream>>>(binned, gcnt, bbase, width, cap, N, rp, srcs);

    // lin1 -> combined rows
    lin1_relu<<<(N + 31) / 32, 256, 0, stream>>>(x, W1, b1, (__half*)hr_a, N);

    // 4 AGNN steps (4 sub-lanes per dst, forced 4 blocks/CU)
    int gs = (N + 63) / 64;
    agnn_step<<<gs, 256, 0, stream>>>(hr_a, rp, srcs, nullptr, hr_b, N);
    agnn_step<<<gs, 256, 0, stream>>>(hr_b, rp, srcs, beta2, hr_a, N);
    agnn_step<<<gs, 256, 0, stream>>>(hr_a, rp, srcs, beta3, hr_b, N);
    agnn_step<<<gs, 256, 0, stream>>>(hr_b, rp, srcs, beta4, hr_a, N);

    // head
    head_kernel<<<(N + 255) / 256, 256, 0, stream>>>(hr_a, W2, b2, out, N);
}

// Round 9
// 552.411 us; speedup vs baseline: 1.6492x; 1.3484x over previous
//
#include <hip/hip_runtime.h>
#include <hip/hip_fp16.h>
#include <math.h>

#define F 512
#define H 16
#define C 7
#define NB 512          // coarse buckets for CSR build
#define BIN_CHUNK 4096  // edges per block in bin_edges
#define BIN_T 512       // threads per bin_edges block (8 waves -> occupancy fix, r4 win)

typedef _Float16 h2 __attribute__((ext_vector_type(2)));

__device__ __forceinline__ h2 as_h2(unsigned u) { return __builtin_bit_cast(h2, u); }
__device__ __forceinline__ unsigned as_u32(h2 v) { return __builtin_bit_cast(unsigned, v); }

__device__ __forceinline__ float dot2acc(h2 a, h2 b, float c) {
#if __has_builtin(__builtin_amdgcn_fdot2)
    return __builtin_amdgcn_fdot2(a, b, c, false);
#else
    return c + (float)a[0] * (float)b[0] + (float)a[1] * (float)b[1];
#endif
}

__device__ __forceinline__ float rsq(float x) {
#if __has_builtin(__builtin_amdgcn_rsqf)
    return __builtin_amdgcn_rsqf(x);
#else
    return rsqrtf(x);
#endif
}

// ---------------- utility ----------------
__global__ void zero_i32(int* p, int n) {
    int i = blockIdx.x * blockDim.x + threadIdx.x;
    if (i < n) p[i] = 0;
}

// ---------------- CSR build: 3 kernels, fixed-capacity buckets (r4 champion, plain loads) ----------------
__global__ __launch_bounds__(BIN_T) void bin_edges(const int* __restrict__ ei, int E, int Etot,
                                                   int width, int cap, int* __restrict__ gcnt,
                                                   unsigned* __restrict__ binned) {
    __shared__ int cnt[NB];
    __shared__ int base[NB];
    int t = threadIdx.x;
    for (int i = t; i < NB; i += BIN_T) cnt[i] = 0;
    __syncthreads();
    long chunk0 = (long)blockIdx.x * BIN_CHUNK;
    for (int k = 0; k < BIN_CHUNK / BIN_T; ++k) {
        long e = chunk0 + k * BIN_T + t;
        if (e < Etot) {
            int dst = (e < E) ? ei[E + e] : (int)(e - E);
            atomicAdd(&cnt[dst / width], 1);
        }
    }
    __syncthreads();
    for (int i = t; i < NB; i += BIN_T) {
        int c = cnt[i];
        base[i] = c ? atomicAdd(&gcnt[i], c) : 0;
        cnt[i] = 0;
    }
    __syncthreads();
    for (int k = 0; k < BIN_CHUNK / BIN_T; ++k) {
        long e = chunk0 + k * BIN_T + t;
        if (e < Etot) {
            int src, dst;
            if (e < E) { src = ei[e]; dst = ei[E + e]; }
            else       { src = (int)(e - E); dst = src; }
            int b = dst / width;
            size_t pos = (size_t)b * cap + base[b] + atomicAdd(&cnt[b], 1);
            binned[pos] = (unsigned)src | ((unsigned)(dst - b * width) << 17);
        }
    }
}

__global__ void bucket_scan(const int* __restrict__ gcnt, int Etot,
                            int* __restrict__ bbase, int* __restrict__ rp, int N) {
    __shared__ int s[NB];
    int t = threadIdx.x;
    int own = gcnt[t];
    s[t] = own;
    __syncthreads();
    for (int d = 1; d < NB; d <<= 1) {
        int add = (t >= d) ? s[t - d] : 0;
        __syncthreads();
        s[t] += add;
        __syncthreads();
    }
    bbase[t] = s[t] - own;
    if (t == NB - 1) bbase[NB] = s[t];
    if (t == 0) rp[N] = Etot;
}

__global__ __launch_bounds__(256) void bucket_sort(const unsigned* __restrict__ binned,
                                                   const int* __restrict__ gcnt,
                                                   const int* __restrict__ bbase,
                                                   int width, int cap, int N,
                                                   int* __restrict__ rp, int* __restrict__ srcs) {
    __shared__ int cnt[256];
    __shared__ int cur[256];
    int b = blockIdx.x, t = threadIdx.x;
    int r0 = bbase[b];
    int ne = gcnt[b];
    const unsigned* bin = binned + (size_t)b * cap;
    int nodeBase = b * width;
    cnt[t] = 0;
    cur[t] = 0;
    __syncthreads();
    for (int e = t; e < ne; e += 256) {
        atomicAdd(&cnt[bin[e] >> 17], 1);
    }
    __syncthreads();
    int own = cnt[t];
    for (int d = 1; d < 256; d <<= 1) {
        int add = (t >= d) ? cnt[t - d] : 0;
        __syncthreads();
        cnt[t] += add;
        __syncthreads();
    }
    int excl = cnt[t] - own;
    int node = nodeBase + t;
    if (t < width && node < N) rp[node] = r0 + excl;
    __syncthreads();
    cnt[t] = excl;
    __syncthreads();
    for (int e = t; e < ne; e += 256) {
        unsigned p = bin[e];
        int dL = p >> 17;
        int pos = r0 + cnt[dL] + atomicAdd(&cur[dL], 1);
        srcs[pos] = (int)(p & 0x1FFFFu);
    }
}

// ---------------- lin1: h = relu(x@W1^T+b1); 32B rows of raw h (fp16 x16), no norms ----------------
__global__ __launch_bounds__(256) void lin1_relu(const float* __restrict__ x,
                                                 const float* __restrict__ W1,
                                                 const float* __restrict__ b1,
                                                 __half* __restrict__ hrow, int N) {
    __shared__ float4 w4[16 * 16 * 9];  // [j][s][m], slice stride 9 float4
    int t = threadIdx.x;
    for (int r = 0; r < 8; ++r) {
        int idx = r * 256 + t;
        int j = idx >> 7;
        int rem = idx & 127;
        int s = rem >> 3, m = rem & 7;
        w4[(j * 16 + s) * 9 + m] = ((const float4*)W1)[idx];
    }
    __syncthreads();

    int s = t & 15, g = t >> 4;
    int iA = blockIdx.x * 32 + g;
    int iB = iA + 16;
    int iAc = min(iA, N - 1), iBc = min(iB, N - 1);

    const float4* xA4 = (const float4*)(x + (size_t)iAc * F);
    const float4* xB4 = (const float4*)(x + (size_t)iBc * F);
    float4 xa[8], xb[8];
#pragma unroll
    for (int m = 0; m < 8; ++m) xa[m] = xA4[s * 8 + m];
#pragma unroll
    for (int m = 0; m < 8; ++m) xb[m] = xB4[s * 8 + m];

    float vA[16], vB[16];
#pragma unroll
    for (int j = 0; j < 16; ++j) { vA[j] = 0.f; vB[j] = 0.f; }
#pragma unroll
    for (int j = 0; j < 16; ++j) {
        const float4* wr = &w4[(j * 16 + s) * 9];
#pragma unroll
        for (int m = 0; m < 8; ++m) {
            float4 w = wr[m];
            vA[j] += w.x * xa[m].x + w.y * xa[m].y + w.z * xa[m].z + w.w * xa[m].w;
            vB[j] += w.x * xb[m].x + w.y * xb[m].y + w.z * xb[m].z + w.w * xb[m].w;
        }
    }

#pragma unroll
    for (int st = 0; st < 4; ++st) {
        int bit = (s >> st) & 1;
        int cntj = 16 >> (st + 1);
#pragma unroll
        for (int k = 0; k < 8; ++k) {
            if (k < cntj) {
                float keepA = bit ? vA[2 * k + 1] : vA[2 * k];
                float giveA = bit ? vA[2 * k] : vA[2 * k + 1];
                vA[k] = keepA + __shfl_xor(giveA, 1 << st);
                float keepB = bit ? vB[2 * k + 1] : vB[2 * k];
                float giveB = bit ? vB[2 * k] : vB[2 * k + 1];
                vB[k] = keepB + __shfl_xor(giveB, 1 << st);
            }
        }
    }

    float bs = b1[s];
    float oA = fmaxf(vA[0] + bs, 0.f);
    float oB = fmaxf(vB[0] + bs, 0.f);

    if (iA < N) hrow[(size_t)iA * 16 + s] = __float2half(oA);
    if (iB < N) hrow[(size_t)iB * 16 + s] = __float2half(oB);
}

// ---------------- AGNN step v10: 4 sub-lanes per dst; 32B raw-h rows (3.2MB table, L2-resident);
// norms computed on the fly. Plain loads/stores (r3's structure MINUS all nt hints).
// w = exp2(aL * (<h_d,h_s> * rn_d * rn_s) - mm);  acc += w * h_s  (identical math to reference)
__global__ __launch_bounds__(256) void agnn_step(const uint4* __restrict__ hrow,
                                                 const int* __restrict__ rp,
                                                 const int* __restrict__ srcs,
                                                 const float* __restrict__ bp,
                                                 uint4* __restrict__ hrow_out, int N) {
    int t = threadIdx.x;
    int sub = t & 3, g = t >> 2;
    int i = blockIdx.x * 64 + g;
    if (i >= N) return;

    const float L2E = 1.4426950408889634f;
    float beta = bp ? bp[0] : 1.0f;
    float aL = beta * L2E;
    float mm = fabsf(beta) * L2E;   // |cos|<=1 -> global bound replaces segment max

    // own raw row (32B)
    const uint4* ri = hrow + (size_t)i * 2;
    uint4 hA = ri[0];
    uint4 hB = ri[1];
    h2 hi[8];
    hi[0] = as_h2(hA.x); hi[1] = as_h2(hA.y); hi[2] = as_h2(hA.z); hi[3] = as_h2(hA.w);
    hi[4] = as_h2(hB.x); hi[5] = as_h2(hB.y); hi[6] = as_h2(hB.z); hi[7] = as_h2(hB.w);

    float sd = 0.f;
#pragma unroll
    for (int q = 0; q < 8; ++q) sd = dot2acc(hi[q], hi[q], sd);
    float c0 = aL * rsq(fmaxf(sd, 1e-24f));   // aL * (1/||h_i||)

    int e0 = rp[i];
    int deg = rp[i + 1] - e0;
    int dm1 = deg - 1;
    int U = (deg + 3) >> 2;   // uniform across the 4 sub-lanes of this dst

    // ring: slot u holds row of edge m=mb+u (lane edge k = sub+4m); sbuf[u] = src of edge m+4
    int sbuf[4];
    uint4 rb0[4], rb1[4];
#pragma unroll
    for (int u = 0; u < 4; ++u) {
        int s = srcs[e0 + min(sub + 4 * u, dm1)];
        const uint4* r = hrow + (size_t)s * 2;
        rb0[u] = r[0]; rb1[u] = r[1];
        sbuf[u] = srcs[e0 + min(sub + 4 * (u + 4), dm1)];
    }

    float denom = 0.f;
    float acc[16];
#pragma unroll
    for (int j = 0; j < 16; ++j) acc[j] = 0.f;

    for (int mb = 0; mb < U; mb += 4) {
#pragma unroll
        for (int u = 0; u < 4; ++u) {
            int m = mb + u;
            int k = sub + 4 * m;
            uint4 a = rb0[u], b = rb1[u];
            // refill slot u with row of edge m+4; prefetch src of edge m+8
            int snext = sbuf[u];
            sbuf[u] = srcs[e0 + min(sub + 4 * (m + 8), dm1)];
            const uint4* r = hrow + (size_t)snext * 2;
            rb0[u] = r[0]; rb1[u] = r[1];

            h2 a0 = as_h2(a.x), a1 = as_h2(a.y), a2 = as_h2(a.z), a3 = as_h2(a.w);
            h2 b0 = as_h2(b.x), b1h = as_h2(b.y), b2h = as_h2(b.z), b3 = as_h2(b.w);

            float cross = 0.f, ss = 0.f;
            cross = dot2acc(hi[0], a0, cross);  ss = dot2acc(a0, a0, ss);
            cross = dot2acc(hi[1], a1, cross);  ss = dot2acc(a1, a1, ss);
            cross = dot2acc(hi[2], a2, cross);  ss = dot2acc(a2, a2, ss);
            cross = dot2acc(hi[3], a3, cross);  ss = dot2acc(a3, a3, ss);
            cross = dot2acc(hi[4], b0, cross);  ss = dot2acc(b0, b0, ss);
            cross = dot2acc(hi[5], b1h, cross); ss = dot2acc(b1h, b1h, ss);
            cross = dot2acc(hi[6], b2h, cross); ss = dot2acc(b2h, b2h, ss);
            cross = dot2acc(hi[7], b3, cross);  ss = dot2acc(b3, b3, ss);

            float rs = rsq(fmaxf(ss, 1e-24f));            // 1/||h_s||
            float w = exp2f(fmaf(cross * rs, c0, -mm));   // exp2(aL*cos - mm)
            w = (k < deg) ? w : 0.f;
            denom += w;

            acc[0]  = fmaf(w, (float)a0[0], acc[0]);
            acc[1]  = fmaf(w, (float)a0[1], acc[1]);
            acc[2]  = fmaf(w, (float)a1[0], acc[2]);
            acc[3]  = fmaf(w, (float)a1[1], acc[3]);
            acc[4]  = fmaf(w, (float)a2[0], acc[4]);
            acc[5]  = fmaf(w, (float)a2[1], acc[5]);
            acc[6]  = fmaf(w, (float)a3[0], acc[6]);
            acc[7]  = fmaf(w, (float)a3[1], acc[7]);
            acc[8]  = fmaf(w, (float)b0[0], acc[8]);
            acc[9]  = fmaf(w, (float)b0[1], acc[9]);
            acc[10] = fmaf(w, (float)b1h[0], acc[10]);
            acc[11] = fmaf(w, (float)b1h[1], acc[11]);
            acc[12] = fmaf(w, (float)b2h[0], acc[12]);
            acc[13] = fmaf(w, (float)b2h[1], acc[13]);
            acc[14] = fmaf(w, (float)b3[0], acc[14]);
            acc[15] = fmaf(w, (float)b3[1], acc[15]);
        }
    }

    // combine the 4 sub-lanes (lanes 4g..4g+3)
    denom += __shfl_xor(denom, 1);
    denom += __shfl_xor(denom, 2);
#pragma unroll
    for (int j = 0; j < 16; ++j) {
        acc[j] += __shfl_xor(acc[j], 1);
        acc[j] += __shfl_xor(acc[j], 2);
    }

    float rd = 1.0f / denom;

    // sub0 writes h[0..7], sub1 writes h[8..15]; full 32B row covered collectively (plain store)
    if (sub < 2) {
        int half = sub * 8;
        uint4 wq;
        h2 t0, t1;
        t0[0] = (_Float16)(acc[half + 0] * rd); t0[1] = (_Float16)(acc[half + 1] * rd);
        t1[0] = (_Float16)(acc[half + 2] * rd); t1[1] = (_Float16)(acc[half + 3] * rd);
        wq.x = as_u32(t0); wq.y = as_u32(t1);
        t0[0] = (_Float16)(acc[half + 4] * rd); t0[1] = (_Float16)(acc[half + 5] * rd);
        t1[0] = (_Float16)(acc[half + 6] * rd); t1[1] = (_Float16)(acc[half + 7] * rd);
        wq.z = as_u32(t0); wq.w = as_u32(t1);
        hrow_out[(size_t)i * 2 + sub] = wq;
    }
}

// ---------------- head: logits + log_softmax (raw h rows, 32B) ----------------
__global__ __launch_bounds__(256) void head_kernel(const uint4* __restrict__ hn,
                                                   const float* __restrict__ W2,
                                                   const float* __restrict__ b2,
                                                   float* __restrict__ out, int N) {
    __shared__ float w2[C * H];
    __shared__ float bb[C];
    int t = threadIdx.x;
    if (t < C * H) w2[t] = W2[t];
    if (t < C) bb[t] = b2[t];
    __syncthreads();
    int i = blockIdx.x * blockDim.x + t;
    if (i >= N) return;
    const uint4* r = hn + (size_t)i * 2;
    uint4 cA = r[0];
    uint4 cB = r[1];
    float hv[H];
    {
        h2 v;
        v = as_h2(cA.x); hv[0] = (float)v[0];  hv[1] = (float)v[1];
        v = as_h2(cA.y); hv[2] = (float)v[0];  hv[3] = (float)v[1];
        v = as_h2(cA.z); hv[4] = (float)v[0];  hv[5] = (float)v[1];
        v = as_h2(cA.w); hv[6] = (float)v[0];  hv[7] = (float)v[1];
        v = as_h2(cB.x); hv[8] = (float)v[0];  hv[9] = (float)v[1];
        v = as_h2(cB.y); hv[10] = (float)v[0]; hv[11] = (float)v[1];
        v = as_h2(cB.z); hv[12] = (float)v[0]; hv[13] = (float)v[1];
        v = as_h2(cB.w); hv[14] = (float)v[0]; hv[15] = (float)v[1];
    }
    float lg[C];
    float m = -1e30f;
#pragma unroll
    for (int c = 0; c < C; ++c) {
        float s = bb[c];
#pragma unroll
        for (int k = 0; k < H; ++k) s += hv[k] * w2[c * H + k];
        lg[c] = s;
        m = fmaxf(m, s);
    }
    float sum = 0.f;
#pragma unroll
    for (int c = 0; c < C; ++c) sum += expf(lg[c] - m);
    float lse = m + logf(sum);
    float* op = out + (size_t)i * C;
#pragma unroll
    for (int c = 0; c < C; ++c) op[c] = lg[c] - lse;
}

// ---------------- launch ----------------
extern "C" void kernel_launch(void* const* d_in, const int* in_sizes, int n_in,
                              void* d_out, int out_size, void* d_ws, size_t ws_size,
                              hipStream_t stream) {
    const float* x     = (const float*)d_in[0];
    const int*   ei    = (const int*)d_in[1];
    const float* W1    = (const float*)d_in[2];
    const float* b1    = (const float*)d_in[3];
    const float* beta2 = (const float*)d_in[4];
    const float* beta3 = (const float*)d_in[5];
    const float* beta4 = (const float*)d_in[6];
    const float* W2    = (const float*)d_in[7];
    const float* b2    = (const float*)d_in[8];
    float* out = (float*)d_out;

    int N = in_sizes[0] / F;     // 100000
    int E = in_sizes[1] / 2;     // 3200000
    int Etot = E + N;
    int width = (N + NB - 1) / NB;   // 196
    int cap = (Etot / NB) * 5 / 4;   // 1.25x mean bucket size (>20 sigma margin)

    char* p = (char*)d_ws;
    uint4* hr_a = (uint4*)p; p += (size_t)N * 32;
    uint4* hr_b = (uint4*)p; p += (size_t)N * 32;
    int* rp     = (int*)p;   p += (size_t)(N + 1) * 4;
    int* srcs   = (int*)p;   p += (size_t)Etot * 4;
    int* gcnt   = (int*)p;   p += (size_t)NB * 4;
    int* bbase  = (int*)p;   p += (size_t)(NB + 1) * 4;
    p = (char*)(((size_t)p + 255) & ~(size_t)255);
    unsigned* binned = (unsigned*)p; p += (size_t)NB * cap * 4;

    // CSR build
    zero_i32<<<(NB + 255) / 256, 256, 0, stream>>>(gcnt, NB);
    bin_edges<<<(Etot + BIN_CHUNK - 1) / BIN_CHUNK, BIN_T, 0, stream>>>(ei, E, Etot, width, cap, gcnt, binned);
    bucket_scan<<<1, NB, 0, stream>>>(gcnt, Etot, bbase, rp, N);
    bucket_sort<<<NB, 256, 0, stream>>>(binned, gcnt, bbase, width, cap, N, rp, srcs);

    // lin1 -> raw h rows (32B)
    lin1_relu<<<(N + 31) / 32, 256, 0, stream>>>(x, W1, b1, (__half*)hr_a, N);

    // 4 AGNN steps (4 sub-lanes per dst)
    int gs = (N + 63) / 64;
    agnn_step<<<gs, 256, 0, stream>>>(hr_a, rp, srcs, nullptr, hr_b, N);
    agnn_step<<<gs, 256, 0, stream>>>(hr_b, rp, srcs, beta2, hr_a, N);
    agnn_step<<<gs, 256, 0, stream>>>(hr_a, rp, srcs, beta3, hr_b, N);
    agnn_step<<<gs, 256, 0, stream>>>(hr_b, rp, srcs, beta4, hr_a, N);

    // head
    head_kernel<<<(N + 255) / 256, 256, 0, stream>>>(hr_a, W2, b2, out, N);
}

// Round 10
// 546.379 us; speedup vs baseline: 1.6674x; 1.0110x over previous
//
#include <hip/hip_runtime.h>
#include <hip/hip_fp16.h>
#include <math.h>

#define F 512
#define H 16
#define C 7
#define NB 512          // coarse buckets for CSR build
#define BIN_CHUNK 4096  // edges per block in bin_edges
#define BIN_T 512       // threads per bin_edges block (r4 occupancy win)
#define BS_T 512        // threads per bucket_sort block (r10: same occupancy fix)

typedef _Float16 h2 __attribute__((ext_vector_type(2)));

__device__ __forceinline__ h2 as_h2(unsigned u) { return __builtin_bit_cast(h2, u); }
__device__ __forceinline__ unsigned as_u32(h2 v) { return __builtin_bit_cast(unsigned, v); }

__device__ __forceinline__ float dot2acc(h2 a, h2 b, float c) {
#if __has_builtin(__builtin_amdgcn_fdot2)
    return __builtin_amdgcn_fdot2(a, b, c, false);
#else
    return c + (float)a[0] * (float)b[0] + (float)a[1] * (float)b[1];
#endif
}

__device__ __forceinline__ float rsq(float x) {
#if __has_builtin(__builtin_amdgcn_rsqf)
    return __builtin_amdgcn_rsqf(x);
#else
    return rsqrtf(x);
#endif
}

// ---------------- utility ----------------
__global__ void zero_i32(int* p, int n) {
    int i = blockIdx.x * blockDim.x + threadIdx.x;
    if (i < n) p[i] = 0;
}

// ---------------- CSR build: 3 kernels, fixed-capacity buckets ----------------
__global__ __launch_bounds__(BIN_T) void bin_edges(const int* __restrict__ ei, int E, int Etot,
                                                   int width, int cap, int* __restrict__ gcnt,
                                                   unsigned* __restrict__ binned) {
    __shared__ int cnt[NB];
    __shared__ int base[NB];
    int t = threadIdx.x;
    for (int i = t; i < NB; i += BIN_T) cnt[i] = 0;
    __syncthreads();
    long chunk0 = (long)blockIdx.x * BIN_CHUNK;
    for (int k = 0; k < BIN_CHUNK / BIN_T; ++k) {
        long e = chunk0 + k * BIN_T + t;
        if (e < Etot) {
            int dst = (e < E) ? ei[E + e] : (int)(e - E);
            atomicAdd(&cnt[dst / width], 1);
        }
    }
    __syncthreads();
    for (int i = t; i < NB; i += BIN_T) {
        int c = cnt[i];
        base[i] = c ? atomicAdd(&gcnt[i], c) : 0;
        cnt[i] = 0;
    }
    __syncthreads();
    for (int k = 0; k < BIN_CHUNK / BIN_T; ++k) {
        long e = chunk0 + k * BIN_T + t;
        if (e < Etot) {
            int src, dst;
            if (e < E) { src = ei[e]; dst = ei[E + e]; }
            else       { src = (int)(e - E); dst = src; }
            int b = dst / width;
            size_t pos = (size_t)b * cap + base[b] + atomicAdd(&cnt[b], 1);
            binned[pos] = (unsigned)src | ((unsigned)(dst - b * width) << 17);
        }
    }
}

__global__ void bucket_scan(const int* __restrict__ gcnt, int Etot,
                            int* __restrict__ bbase, int* __restrict__ rp, int N) {
    __shared__ int s[NB];
    int t = threadIdx.x;
    int own = gcnt[t];
    s[t] = own;
    __syncthreads();
    for (int d = 1; d < NB; d <<= 1) {
        int add = (t >= d) ? s[t - d] : 0;
        __syncthreads();
        s[t] += add;
        __syncthreads();
    }
    bbase[t] = s[t] - own;
    if (t == NB - 1) bbase[NB] = s[t];
    if (t == 0) rp[N] = Etot;
}

// r10: 512 threads (8 waves) — same occupancy fix that won on bin_edges (r4).
// Edge loops stride BS_T; the 256-entry scan runs on t<256 with all threads at the barriers.
__global__ __launch_bounds__(BS_T) void bucket_sort(const unsigned* __restrict__ binned,
                                                    const int* __restrict__ gcnt,
                                                    const int* __restrict__ bbase,
                                                    int width, int cap, int N,
                                                    int* __restrict__ rp, int* __restrict__ srcs) {
    __shared__ int cnt[256];
    __shared__ int cur[256];
    int b = blockIdx.x, t = threadIdx.x;
    int r0 = bbase[b];
    int ne = gcnt[b];
    const unsigned* bin = binned + (size_t)b * cap;
    int nodeBase = b * width;
    if (t < 256) { cnt[t] = 0; cur[t] = 0; }
    __syncthreads();
    for (int e = t; e < ne; e += BS_T) {
        atomicAdd(&cnt[bin[e] >> 17], 1);
    }
    __syncthreads();
    int own = (t < 256) ? cnt[t] : 0;
    for (int d = 1; d < 256; d <<= 1) {
        int add = (t >= d && t < 256) ? cnt[t - d] : 0;
        __syncthreads();
        if (t < 256) cnt[t] += add;
        __syncthreads();
    }
    int excl = (t < 256) ? (cnt[t] - own) : 0;
    int node = nodeBase + t;
    if (t < width && node < N) rp[node] = r0 + excl;
    __syncthreads();
    if (t < 256) cnt[t] = excl;
    __syncthreads();
    for (int e = t; e < ne; e += BS_T) {
        unsigned p = bin[e];
        int dL = p >> 17;
        int pos = r0 + cnt[dL] + atomicAdd(&cur[dL], 1);
        srcs[pos] = (int)(p & 0x1FFFFu);
    }
}

// ---------------- lin1: h = relu(x@W1^T+b1); 32B rows of raw h (fp16 x16), no norms ----------------
__global__ __launch_bounds__(256) void lin1_relu(const float* __restrict__ x,
                                                 const float* __restrict__ W1,
                                                 const float* __restrict__ b1,
                                                 __half* __restrict__ hrow, int N) {
    __shared__ float4 w4[16 * 16 * 9];  // [j][s][m], slice stride 9 float4
    int t = threadIdx.x;
    for (int r = 0; r < 8; ++r) {
        int idx = r * 256 + t;
        int j = idx >> 7;
        int rem = idx & 127;
        int s = rem >> 3, m = rem & 7;
        w4[(j * 16 + s) * 9 + m] = ((const float4*)W1)[idx];
    }
    __syncthreads();

    int s = t & 15, g = t >> 4;
    int iA = blockIdx.x * 32 + g;
    int iB = iA + 16;
    int iAc = min(iA, N - 1), iBc = min(iB, N - 1);

    const float4* xA4 = (const float4*)(x + (size_t)iAc * F);
    const float4* xB4 = (const float4*)(x + (size_t)iBc * F);
    float4 xa[8], xb[8];
#pragma unroll
    for (int m = 0; m < 8; ++m) xa[m] = xA4[s * 8 + m];
#pragma unroll
    for (int m = 0; m < 8; ++m) xb[m] = xB4[s * 8 + m];

    float vA[16], vB[16];
#pragma unroll
    for (int j = 0; j < 16; ++j) { vA[j] = 0.f; vB[j] = 0.f; }
#pragma unroll
    for (int j = 0; j < 16; ++j) {
        const float4* wr = &w4[(j * 16 + s) * 9];
#pragma unroll
        for (int m = 0; m < 8; ++m) {
            float4 w = wr[m];
            vA[j] += w.x * xa[m].x + w.y * xa[m].y + w.z * xa[m].z + w.w * xa[m].w;
            vB[j] += w.x * xb[m].x + w.y * xb[m].y + w.z * xb[m].z + w.w * xb[m].w;
        }
    }

#pragma unroll
    for (int st = 0; st < 4; ++st) {
        int bit = (s >> st) & 1;
        int cntj = 16 >> (st + 1);
#pragma unroll
        for (int k = 0; k < 8; ++k) {
            if (k < cntj) {
                float keepA = bit ? vA[2 * k + 1] : vA[2 * k];
                float giveA = bit ? vA[2 * k] : vA[2 * k + 1];
                vA[k] = keepA + __shfl_xor(giveA, 1 << st);
                float keepB = bit ? vB[2 * k + 1] : vB[2 * k];
                float giveB = bit ? vB[2 * k] : vB[2 * k + 1];
                vB[k] = keepB + __shfl_xor(giveB, 1 << st);
            }
        }
    }

    float bs = b1[s];
    float oA = fmaxf(vA[0] + bs, 0.f);
    float oB = fmaxf(vB[0] + bs, 0.f);

    if (iA < N) hrow[(size_t)iA * 16 + s] = __float2half(oA);
    if (iB < N) hrow[(size_t)iB * 16 + s] = __float2half(oB);
}

// ---------------- AGNN step v10 (r9 champion) + optional fused head on the last step ----------------
// 4 sub-lanes per dst; 32B raw-h rows (3.2MB table, L2-resident); norms on the fly.
// If W2 != nullptr: skip hrow_out write, sub0 computes logits + log_softmax -> out (head fused).
__global__ __launch_bounds__(256) void agnn_step(const uint4* __restrict__ hrow,
                                                 const int* __restrict__ rp,
                                                 const int* __restrict__ srcs,
                                                 const float* __restrict__ bp,
                                                 uint4* __restrict__ hrow_out,
                                                 const float* __restrict__ W2,
                                                 const float* __restrict__ b2,
                                                 float* __restrict__ out, int N) {
    int t = threadIdx.x;
    int sub = t & 3, g = t >> 2;
    int i = blockIdx.x * 64 + g;
    if (i >= N) return;

    const float L2E = 1.4426950408889634f;
    float beta = bp ? bp[0] : 1.0f;
    float aL = beta * L2E;
    float mm = fabsf(beta) * L2E;   // |cos|<=1 -> global bound replaces segment max

    // own raw row (32B)
    const uint4* ri = hrow + (size_t)i * 2;
    uint4 hA = ri[0];
    uint4 hB = ri[1];
    h2 hi[8];
    hi[0] = as_h2(hA.x); hi[1] = as_h2(hA.y); hi[2] = as_h2(hA.z); hi[3] = as_h2(hA.w);
    hi[4] = as_h2(hB.x); hi[5] = as_h2(hB.y); hi[6] = as_h2(hB.z); hi[7] = as_h2(hB.w);

    float sd = 0.f;
#pragma unroll
    for (int q = 0; q < 8; ++q) sd = dot2acc(hi[q], hi[q], sd);
    float c0 = aL * rsq(fmaxf(sd, 1e-24f));   // aL * (1/||h_i||)

    int e0 = rp[i];
    int deg = rp[i + 1] - e0;
    int dm1 = deg - 1;
    int U = (deg + 3) >> 2;   // uniform across the 4 sub-lanes of this dst

    // ring: slot u holds row of edge m=mb+u (lane edge k = sub+4m); sbuf[u] = src of edge m+4
    int sbuf[4];
    uint4 rb0[4], rb1[4];
#pragma unroll
    for (int u = 0; u < 4; ++u) {
        int s = srcs[e0 + min(sub + 4 * u, dm1)];
        const uint4* r = hrow + (size_t)s * 2;
        rb0[u] = r[0]; rb1[u] = r[1];
        sbuf[u] = srcs[e0 + min(sub + 4 * (u + 4), dm1)];
    }

    float denom = 0.f;
    float acc[16];
#pragma unroll
    for (int j = 0; j < 16; ++j) acc[j] = 0.f;

    for (int mb = 0; mb < U; mb += 4) {
#pragma unroll
        for (int u = 0; u < 4; ++u) {
            int m = mb + u;
            int k = sub + 4 * m;
            uint4 a = rb0[u], b = rb1[u];
            // refill slot u with row of edge m+4; prefetch src of edge m+8
            int snext = sbuf[u];
            sbuf[u] = srcs[e0 + min(sub + 4 * (m + 8), dm1)];
            const uint4* r = hrow + (size_t)snext * 2;
            rb0[u] = r[0]; rb1[u] = r[1];

            h2 a0 = as_h2(a.x), a1 = as_h2(a.y), a2 = as_h2(a.z), a3 = as_h2(a.w);
            h2 b0 = as_h2(b.x), b1h = as_h2(b.y), b2h = as_h2(b.z), b3 = as_h2(b.w);

            float cross = 0.f, ss = 0.f;
            cross = dot2acc(hi[0], a0, cross);  ss = dot2acc(a0, a0, ss);
            cross = dot2acc(hi[1], a1, cross);  ss = dot2acc(a1, a1, ss);
            cross = dot2acc(hi[2], a2, cross);  ss = dot2acc(a2, a2, ss);
            cross = dot2acc(hi[3], a3, cross);  ss = dot2acc(a3, a3, ss);
            cross = dot2acc(hi[4], b0, cross);  ss = dot2acc(b0, b0, ss);
            cross = dot2acc(hi[5], b1h, cross); ss = dot2acc(b1h, b1h, ss);
            cross = dot2acc(hi[6], b2h, cross); ss = dot2acc(b2h, b2h, ss);
            cross = dot2acc(hi[7], b3, cross);  ss = dot2acc(b3, b3, ss);

            float rs = rsq(fmaxf(ss, 1e-24f));            // 1/||h_s||
            float w = exp2f(fmaf(cross * rs, c0, -mm));   // exp2(aL*cos - mm)
            w = (k < deg) ? w : 0.f;
            denom += w;

            acc[0]  = fmaf(w, (float)a0[0], acc[0]);
            acc[1]  = fmaf(w, (float)a0[1], acc[1]);
            acc[2]  = fmaf(w, (float)a1[0], acc[2]);
            acc[3]  = fmaf(w, (float)a1[1], acc[3]);
            acc[4]  = fmaf(w, (float)a2[0], acc[4]);
            acc[5]  = fmaf(w, (float)a2[1], acc[5]);
            acc[6]  = fmaf(w, (float)a3[0], acc[6]);
            acc[7]  = fmaf(w, (float)a3[1], acc[7]);
            acc[8]  = fmaf(w, (float)b0[0], acc[8]);
            acc[9]  = fmaf(w, (float)b0[1], acc[9]);
            acc[10] = fmaf(w, (float)b1h[0], acc[10]);
            acc[11] = fmaf(w, (float)b1h[1], acc[11]);
            acc[12] = fmaf(w, (float)b2h[0], acc[12]);
            acc[13] = fmaf(w, (float)b2h[1], acc[13]);
            acc[14] = fmaf(w, (float)b3[0], acc[14]);
            acc[15] = fmaf(w, (float)b3[1], acc[15]);
        }
    }

    // combine the 4 sub-lanes (lanes 4g..4g+3)
    denom += __shfl_xor(denom, 1);
    denom += __shfl_xor(denom, 2);
#pragma unroll
    for (int j = 0; j < 16; ++j) {
        acc[j] += __shfl_xor(acc[j], 1);
        acc[j] += __shfl_xor(acc[j], 2);
    }

    float rd = 1.0f / denom;

    if (W2) {
        // fused head (last step): sub0 computes logits + log_softmax from fp32 acc
        if (sub == 0) {
            float hv[H];
#pragma unroll
            for (int j = 0; j < H; ++j) hv[j] = acc[j] * rd;
            float lg[C];
            float mx = -1e30f;
#pragma unroll
            for (int c = 0; c < C; ++c) {
                float s = b2[c];
#pragma unroll
                for (int k = 0; k < H; ++k) s += hv[k] * W2[c * H + k];
                lg[c] = s;
                mx = fmaxf(mx, s);
            }
            float sum = 0.f;
#pragma unroll
            for (int c = 0; c < C; ++c) sum += expf(lg[c] - mx);
            float lse = mx + logf(sum);
            float* op = out + (size_t)i * C;
#pragma unroll
            for (int c = 0; c < C; ++c) op[c] = lg[c] - lse;
        }
        return;
    }

    // sub0 writes h[0..7], sub1 writes h[8..15]; full 32B row covered collectively
    if (sub < 2) {
        int half = sub * 8;
        uint4 wq;
        h2 t0, t1;
        t0[0] = (_Float16)(acc[half + 0] * rd); t0[1] = (_Float16)(acc[half + 1] * rd);
        t1[0] = (_Float16)(acc[half + 2] * rd); t1[1] = (_Float16)(acc[half + 3] * rd);
        wq.x = as_u32(t0); wq.y = as_u32(t1);
        t0[0] = (_Float16)(acc[half + 4] * rd); t0[1] = (_Float16)(acc[half + 5] * rd);
        t1[0] = (_Float16)(acc[half + 6] * rd); t1[1] = (_Float16)(acc[half + 7] * rd);
        wq.z = as_u32(t0); wq.w = as_u32(t1);
        hrow_out[(size_t)i * 2 + sub] = wq;
    }
}

// ---------------- launch ----------------
extern "C" void kernel_launch(void* const* d_in, const int* in_sizes, int n_in,
                              void* d_out, int out_size, void* d_ws, size_t ws_size,
                              hipStream_t stream) {
    const float* x     = (const float*)d_in[0];
    const int*   ei    = (const int*)d_in[1];
    const float* W1    = (const float*)d_in[2];
    const float* b1    = (const float*)d_in[3];
    const float* beta2 = (const float*)d_in[4];
    const float* beta3 = (const float*)d_in[5];
    const float* beta4 = (const float*)d_in[6];
    const float* W2    = (const float*)d_in[7];
    const float* b2    = (const float*)d_in[8];
    float* out = (float*)d_out;

    int N = in_sizes[0] / F;     // 100000
    int E = in_sizes[1] / 2;     // 3200000
    int Etot = E + N;
    int width = (N + NB - 1) / NB;   // 196
    int cap = (Etot / NB) * 5 / 4;   // 1.25x mean bucket size (>20 sigma margin)

    char* p = (char*)d_ws;
    uint4* hr_a = (uint4*)p; p += (size_t)N * 32;
    uint4* hr_b = (uint4*)p; p += (size_t)N * 32;
    int* rp     = (int*)p;   p += (size_t)(N + 1) * 4;
    int* srcs   = (int*)p;   p += (size_t)Etot * 4;
    int* gcnt   = (int*)p;   p += (size_t)NB * 4;
    int* bbase  = (int*)p;   p += (size_t)(NB + 1) * 4;
    p = (char*)(((size_t)p + 255) & ~(size_t)255);
    unsigned* binned = (unsigned*)p; p += (size_t)NB * cap * 4;

    // CSR build
    zero_i32<<<(NB + 255) / 256, 256, 0, stream>>>(gcnt, NB);
    bin_edges<<<(Etot + BIN_CHUNK - 1) / BIN_CHUNK, BIN_T, 0, stream>>>(ei, E, Etot, width, cap, gcnt, binned);
    bucket_scan<<<1, NB, 0, stream>>>(gcnt, Etot, bbase, rp, N);
    bucket_sort<<<NB, BS_T, 0, stream>>>(binned, gcnt, bbase, width, cap, N, rp, srcs);

    // lin1 -> raw h rows (32B)
    lin1_relu<<<(N + 31) / 32, 256, 0, stream>>>(x, W1, b1, (__half*)hr_a, N);

    // 4 AGNN steps (4 sub-lanes per dst); head fused into the last step
    int gs = (N + 63) / 64;
    agnn_step<<<gs, 256, 0, stream>>>(hr_a, rp, srcs, nullptr, hr_b, nullptr, nullptr, nullptr, N);
    agnn_step<<<gs, 256, 0, stream>>>(hr_b, rp, srcs, beta2, hr_a, nullptr, nullptr, nullptr, N);
    agnn_step<<<gs, 256, 0, stream>>>(hr_a, rp, srcs, beta3, hr_b, nullptr, nullptr, nullptr, N);
    agnn_step<<<gs, 256, 0, stream>>>(hr_b, rp, srcs, beta4, nullptr, W2, b2, out, N);
}